// Round 2
// baseline (657.853 us; speedup 1.0000x reference)
//
#include <hip/hip_runtime.h>
#include <cstdint>
#include <cstddef>

// MultiResHashGrid encode: 1e6 points, 16 levels, 2 feats/level, 2^19 hashmap.
// Output per point: [x,y,z, f(l0,0),f(l0,1), ..., f(l15,0),f(l15,1)] = 35 f32.
//
// R3 strategy (on top of R2's level-major two-pass):
//   Pass1: - corner PAIRING: x-dim hash prime is 1, so corners (2k,2k+1) hash
//            to {h, h^1} when xi is even; every hs is even so the pair lives in
//            two ADJACENT 16B-aligned entries -> one dwordx4 serves two corners.
//            4 unconditional x4-loads + 4 divergent x2-loads for odd-xi lanes
//            = 384 line-requests/wave/level vs 512 (-25% on the request-bound path).
//          - non-temporal x loads + ws stores: stop evicting the 4MB table
//            that exactly fills each XCD L2 -> higher gather hit rate.
//   Pass2: barrier-free wave-private 64-point LDS tiles (1e6 % 64 == 0),
//          non-temporal ws loads + out stores. Waves no longer convoy behind
//          each other's cold HBM misses at a block barrier.
//
// NOTE: __builtin_nontemporal_* requires native vector types, not HIP's
// float2/float4 classes -> use ext_vector_type typedefs at those sites.

#define NPTS     1000000
#define NLEV     16
#define TBL_ENT  524288      // 2^19 entries per level
#define BLK      256
#define OUT_PP   35          // floats per point
#define CHUNKS   ((NPTS + BLK - 1) / BLK)   // 3907
#define TILES    (NPTS / 64)                // 15625 (exact)
#define P2BLOCKS ((TILES + (BLK/64) - 1) / (BLK/64))   // 3907

typedef float f32x2 __attribute__((ext_vector_type(2)));
typedef float f32x4 __attribute__((ext_vector_type(4)));

// r:  16  22  30  42  58  80  111  153  212  294  406  561  776  1072 1482 2048
// hs: min(r^3, 2^19)
constexpr float    cRes[NLEV] = {16.f, 22.f, 30.f, 42.f, 58.f, 80.f, 111.f, 153.f,
                                 212.f, 294.f, 406.f, 561.f, 776.f, 1072.f, 1482.f, 2048.f};
constexpr uint32_t cHS[NLEV]  = {4096u, 10648u, 27000u, 74088u, 195112u, 512000u,
                                 524288u, 524288u, 524288u, 524288u, 524288u,
                                 524288u, 524288u, 524288u, 524288u, 524288u};

// ---------------- per-level gather, compile-time level params ----------------
//
// Hashes: h(c) = (xi + cx) ^ (yi+cy)*P2 ^ (zi+cz)*P3, hid = h % hs.
// For the corner pair (2k, 2k+1) sharing (cy,cz): if xi even, h(2k+1) = h(2k)^1.
// hs is even for every level, so entries {(h&~1)%hs, (h&~1)%hs + 1} are the two
// table slots of the pair, adjacent and 16B-aligned -> single float4 load.
// Corner 2k is ALWAYS one of the two halves (select by h&1), any xi parity.

template<int L>
__device__ __forceinline__ void do_level(float px, float py, float pz,
                                         const float* __restrict__ tables,
                                         float& f0, float& f1)
{
    constexpr float    r  = cRes[L];
    constexpr uint32_t hs = cHS[L];
    const float2* __restrict__ tbl =
        reinterpret_cast<const float2*>(tables) + (size_t)L * TBL_ENT;

    const float xs = px * r, ys = py * r, zs = pz * r;
    const int xi = (int)xs, yi = (int)ys, zi = (int)zs;
    const float xf = xs - (float)xi, yf = ys - (float)yi, zf = zs - (float)zi;

    const uint32_t hx0 = (uint32_t)xi;
    const uint32_t hy0 = (uint32_t)yi * 2654435761u;
    const uint32_t hz0 = (uint32_t)zi * 805459861u;
    const uint32_t hy1 = hy0 + 2654435761u;
    const uint32_t hz1 = hz0 + 805459861u;

    const bool xodd = (xi & 1) != 0;

    const float wx0 = 1.f - xf, wx1 = xf;
    const float wy0 = 1.f - yf, wy1 = yf;
    const float wz0 = 1.f - zf, wz1 = zf;

    float2 v[8];

    // 4 unconditional paired loads (one per (y,z) corner combo)
    #pragma unroll
    for (int k = 0; k < 4; ++k) {
        const uint32_t hyz = ((k & 1) ? hy1 : hy0) ^ ((k & 2) ? hz1 : hz0);
        const uint32_t h0  = hx0 ^ hyz;            // corner 2k hash
        const uint32_t e   = (h0 & ~1u) % hs;      // even entry of the pair
        const float4 q = *reinterpret_cast<const float4*>(
                             reinterpret_cast<const float*>(tbl + e));
        const bool oh = (h0 & 1u) != 0;
        const float2 a = make_float2(q.x, q.y);    // entry e   (hash parity 0)
        const float2 b = make_float2(q.z, q.w);    // entry e+1 (hash parity 1)
        v[2*k]   = oh ? b : a;                     // corner 2k: always correct
        v[2*k+1] = oh ? a : b;                     // correct iff xi even
    }

    // odd-xi lanes: corner 2k+1 hash is (xi+1)^hyz, a different line
    if (xodd) {
        #pragma unroll
        for (int k = 0; k < 4; ++k) {
            const uint32_t hyz = ((k & 1) ? hy1 : hy0) ^ ((k & 2) ? hz1 : hz0);
            const uint32_t h1  = (hx0 + 1u) ^ hyz;
            v[2*k+1] = tbl[h1 % hs];
        }
    }

    f0 = 0.f; f1 = 0.f;
    #pragma unroll
    for (int c = 0; c < 8; ++c) {
        const float wxc = (c & 1) ? wx1 : wx0;
        const float wyc = (c & 2) ? wy1 : wy0;
        const float wzc = (c & 4) ? wz1 : wz0;
        const float wc  = wxc * wyc * wzc;
        f0 = fmaf(wc, v[c].x, f0);
        f1 = fmaf(wc, v[c].y, f1);
    }
}

// ---------------- Pass 1: level-major gather ----------------

__global__ __launch_bounds__(BLK) void hashgrid_pass1(
    const float* __restrict__ x,
    const float* __restrict__ tables,
    float2* __restrict__ ws)
{
    const int b = blockIdx.x;
    const int l = b / CHUNKS;          // level (block-uniform)
    const int c = b - l * CHUNKS;      // point chunk
    const int i = c * BLK + threadIdx.x;
    if (i >= NPTS) return;

    // nt: x is served by L3 across level passes; keep it out of the table's L2
    const float px = __builtin_nontemporal_load(&x[3 * i + 0]);
    const float py = __builtin_nontemporal_load(&x[3 * i + 1]);
    const float pz = __builtin_nontemporal_load(&x[3 * i + 2]);

    float f0, f1;
    switch (l) {
        case 0:  do_level<0 >(px, py, pz, tables, f0, f1); break;
        case 1:  do_level<1 >(px, py, pz, tables, f0, f1); break;
        case 2:  do_level<2 >(px, py, pz, tables, f0, f1); break;
        case 3:  do_level<3 >(px, py, pz, tables, f0, f1); break;
        case 4:  do_level<4 >(px, py, pz, tables, f0, f1); break;
        case 5:  do_level<5 >(px, py, pz, tables, f0, f1); break;
        case 6:  do_level<6 >(px, py, pz, tables, f0, f1); break;
        case 7:  do_level<7 >(px, py, pz, tables, f0, f1); break;
        case 8:  do_level<8 >(px, py, pz, tables, f0, f1); break;
        case 9:  do_level<9 >(px, py, pz, tables, f0, f1); break;
        case 10: do_level<10>(px, py, pz, tables, f0, f1); break;
        case 11: do_level<11>(px, py, pz, tables, f0, f1); break;
        case 12: do_level<12>(px, py, pz, tables, f0, f1); break;
        case 13: do_level<13>(px, py, pz, tables, f0, f1); break;
        case 14: do_level<14>(px, py, pz, tables, f0, f1); break;
        default: do_level<15>(px, py, pz, tables, f0, f1); break;
    }

    // nt: written once, read once (pass2); don't evict the table
    f32x2 o; o.x = f0; o.y = f1;
    __builtin_nontemporal_store(o,
        reinterpret_cast<f32x2*>(ws) + (size_t)l * NPTS + i);
}

// ---------------- Pass 2: wave-private transpose, barrier-free ----------------

__global__ __launch_bounds__(BLK) void hashgrid_pass2(
    const float* __restrict__ x,
    const float2* __restrict__ ws,
    float* __restrict__ out)
{
    __shared__ float smem[BLK * OUT_PP];   // 4 wave-private 8960B slices

    const int lane = threadIdx.x & 63;
    const int w    = threadIdx.x >> 6;
    const int tile = blockIdx.x * (BLK / 64) + w;   // 64-point tile
    if (tile >= TILES) return;                      // wave-uniform exit
    const int i = tile * 64 + lane;                 // always < NPTS (NPTS%64==0)

    float* s = smem + w * (64 * OUT_PP);

    s[lane * OUT_PP + 0] = __builtin_nontemporal_load(&x[3 * i + 0]);
    s[lane * OUT_PP + 1] = __builtin_nontemporal_load(&x[3 * i + 1]);
    s[lane * OUT_PP + 2] = __builtin_nontemporal_load(&x[3 * i + 2]);
    const f32x2* __restrict__ wsv = reinterpret_cast<const f32x2*>(ws);
    #pragma unroll
    for (int l = 0; l < NLEV; ++l) {
        const f32x2 v = __builtin_nontemporal_load(&wsv[(size_t)l * NPTS + i]);
        s[lane * OUT_PP + 3 + 2 * l]     = v.x;
        s[lane * OUT_PP + 3 + 2 * l + 1] = v.y;
    }

    // wave-private LDS slice: only need this wave's DS ops complete, no barrier
    asm volatile("s_waitcnt lgkmcnt(0)" ::: "memory");

    const f32x4* __restrict__ s4 = reinterpret_cast<const f32x4*>(s);
    f32x4* __restrict__ o4 =
        reinterpret_cast<f32x4*>(out + (size_t)tile * (64 * OUT_PP));
    #pragma unroll
    for (int j = lane; j < (64 * OUT_PP) / 4; j += 64)   // 560 float4 / tile
        __builtin_nontemporal_store(s4[j], &o4[j]);
}

// ---------------- Fallback (point-major single kernel) ----------------

__global__ __launch_bounds__(BLK) void hashgrid_fused(
    const float* __restrict__ x,
    const float* __restrict__ tables,
    float* __restrict__ out)
{
    __shared__ float smem[BLK * OUT_PP];

    const int t = threadIdx.x;
    const int i = blockIdx.x * BLK + t;
    const bool active = (i < NPTS);

    float px = 0.f, py = 0.f, pz = 0.f;
    if (active) {
        px = x[3 * i + 0];
        py = x[3 * i + 1];
        pz = x[3 * i + 2];
    }
    smem[t * OUT_PP + 0] = px;
    smem[t * OUT_PP + 1] = py;
    smem[t * OUT_PP + 2] = pz;

    float f0, f1;
    #pragma unroll
    for (int l = 0; l < NLEV; ++l) {
        switch (l) {
            case 0:  do_level<0 >(px, py, pz, tables, f0, f1); break;
            case 1:  do_level<1 >(px, py, pz, tables, f0, f1); break;
            case 2:  do_level<2 >(px, py, pz, tables, f0, f1); break;
            case 3:  do_level<3 >(px, py, pz, tables, f0, f1); break;
            case 4:  do_level<4 >(px, py, pz, tables, f0, f1); break;
            case 5:  do_level<5 >(px, py, pz, tables, f0, f1); break;
            case 6:  do_level<6 >(px, py, pz, tables, f0, f1); break;
            case 7:  do_level<7 >(px, py, pz, tables, f0, f1); break;
            case 8:  do_level<8 >(px, py, pz, tables, f0, f1); break;
            case 9:  do_level<9 >(px, py, pz, tables, f0, f1); break;
            case 10: do_level<10>(px, py, pz, tables, f0, f1); break;
            case 11: do_level<11>(px, py, pz, tables, f0, f1); break;
            case 12: do_level<12>(px, py, pz, tables, f0, f1); break;
            case 13: do_level<13>(px, py, pz, tables, f0, f1); break;
            case 14: do_level<14>(px, py, pz, tables, f0, f1); break;
            default: do_level<15>(px, py, pz, tables, f0, f1); break;
        }
        smem[t * OUT_PP + 3 + 2 * l]     = f0;
        smem[t * OUT_PP + 3 + 2 * l + 1] = f1;
    }

    __syncthreads();

    const size_t gbase = (size_t)blockIdx.x * (BLK * OUT_PP);
    const long long remain = (long long)NPTS * OUT_PP - (long long)gbase;
    const int n4 = (int)((remain < (long long)(BLK * OUT_PP) ? remain : (long long)(BLK * OUT_PP)) / 4);
    const float4* __restrict__ s4 = reinterpret_cast<const float4*>(smem);
    float4* __restrict__ o4 = reinterpret_cast<float4*>(out + gbase);
    for (int j = t; j < n4; j += BLK) o4[j] = s4[j];
}

extern "C" void kernel_launch(void* const* d_in, const int* in_sizes, int n_in,
                              void* d_out, int out_size, void* d_ws, size_t ws_size,
                              hipStream_t stream)
{
    const float* x      = (const float*)d_in[0];   // (1e6, 3) f32
    const float* tables = (const float*)d_in[1];   // (16, 2^19, 2) f32
    float* out          = (float*)d_out;           // (1e6, 35) f32

    const size_t ws_needed = (size_t)NLEV * NPTS * sizeof(float2);   // 128 MB

    if (ws_size >= ws_needed) {
        float2* ws = (float2*)d_ws;
        hashgrid_pass1<<<NLEV * CHUNKS, BLK, 0, stream>>>(x, tables, ws);
        hashgrid_pass2<<<P2BLOCKS, BLK, 0, stream>>>(x, ws, out);
    } else {
        hashgrid_fused<<<CHUNKS, BLK, 0, stream>>>(x, tables, out);
    }
}

// Round 3
// 555.832 us; speedup vs baseline: 1.1835x; 1.1835x over previous
//
#include <hip/hip_runtime.h>
#include <cstdint>
#include <cstddef>

// MultiResHashGrid encode: 1e6 points, 16 levels, 2 feats/level, 2^19 hashmap.
// Output per point: [x,y,z, f(l0,0),f(l0,1), ..., f(l15,0),f(l15,1)] = 35 f32.
//
// R4: pass1 is VMEM lane-slot bound (R3 post-mortem: +33% when gathers went
// 8B->16B/lane proves per-lane-slot currency, not lines, not HBM bytes).
//   - REVERT corner pairing: 8 independent dwordx2 gathers (8B = 1 slot each
//     is the minimum: 8 entries/point/level is irreducible).
//   - x point load: 3 scalar dwords -> one dwordx3 (12B packed struct):
//     12 -> 10 VMEM instrs per point-level, predicted ~ -16% on pass1.
//   - nt ONLY on stores (ws, out): protects table L2 residency (FETCH 466->400
//     was the one good R3 outcome), cannot slow the load path.
//   - pass2: barrier-free wave-private 64-point LDS tiles (measured neutral,
//     structurally better), dwordx3 x load, nt out stores.

#define NPTS     1000000
#define NLEV     16
#define TBL_ENT  524288      // 2^19 entries per level
#define BLK      256
#define OUT_PP   35          // floats per point
#define CHUNKS   ((NPTS + BLK - 1) / BLK)   // 3907
#define TILES    (NPTS / 64)                // 15625 (exact)
#define P2BLOCKS ((TILES + (BLK/64) - 1) / (BLK/64))   // 3907

typedef float f32x2 __attribute__((ext_vector_type(2)));
typedef float f32x4 __attribute__((ext_vector_type(4)));

// 12B point — loads as global_load_dwordx3 (align 4 ok)
struct F3 { float x, y, z; };

// r:  16  22  30  42  58  80  111  153  212  294  406  561  776  1072 1482 2048
// hs: min(r^3, 2^19)
constexpr float    cRes[NLEV] = {16.f, 22.f, 30.f, 42.f, 58.f, 80.f, 111.f, 153.f,
                                 212.f, 294.f, 406.f, 561.f, 776.f, 1072.f, 1482.f, 2048.f};
constexpr uint32_t cHS[NLEV]  = {4096u, 10648u, 27000u, 74088u, 195112u, 512000u,
                                 524288u, 524288u, 524288u, 524288u, 524288u,
                                 524288u, 524288u, 524288u, 524288u, 524288u};

// ---------------- per-level gather (R2 form), compile-time level params ----------------

template<int L>
__device__ __forceinline__ void do_level(float px, float py, float pz,
                                         const float* __restrict__ tables,
                                         float& f0, float& f1)
{
    constexpr float    r  = cRes[L];
    constexpr uint32_t hs = cHS[L];
    const float2* __restrict__ tbl =
        reinterpret_cast<const float2*>(tables) + (size_t)L * TBL_ENT;

    const float xs = px * r, ys = py * r, zs = pz * r;
    const int xi = (int)xs, yi = (int)ys, zi = (int)zs;
    const float xf = xs - (float)xi, yf = ys - (float)yi, zf = zs - (float)zi;

    const uint32_t hx0 = (uint32_t)xi;
    const uint32_t hx1 = hx0 + 1u;
    const uint32_t hy0 = (uint32_t)yi * 2654435761u;
    const uint32_t hy1 = hy0 + 2654435761u;
    const uint32_t hz0 = (uint32_t)zi * 805459861u;
    const uint32_t hz1 = hz0 + 805459861u;

    const float wx0 = 1.f - xf, wx1 = xf;
    const float wy0 = 1.f - yf, wy1 = yf;
    const float wz0 = 1.f - zf, wz1 = zf;

    uint32_t hid[8];
    float    w[8];
    #pragma unroll
    for (int c = 0; c < 8; ++c) {
        const uint32_t hxc = (c & 1) ? hx1 : hx0;
        const uint32_t hyc = (c & 2) ? hy1 : hy0;
        const uint32_t hzc = (c & 4) ? hz1 : hz0;
        hid[c] = (hxc ^ hyc ^ hzc) % hs;   // hs compile-time: AND or magic-mul
        const float wxc = (c & 1) ? wx1 : wx0;
        const float wyc = (c & 2) ? wy1 : wy0;
        const float wzc = (c & 4) ? wz1 : wz0;
        w[c] = wxc * wyc * wzc;
    }

    float2 v[8];
    #pragma unroll
    for (int c = 0; c < 8; ++c) v[c] = tbl[hid[c]];

    f0 = 0.f; f1 = 0.f;
    #pragma unroll
    for (int c = 0; c < 8; ++c) {
        f0 = fmaf(w[c], v[c].x, f0);
        f1 = fmaf(w[c], v[c].y, f1);
    }
}

// ---------------- Pass 1: level-major gather ----------------

__global__ __launch_bounds__(BLK) void hashgrid_pass1(
    const float* __restrict__ x,
    const float* __restrict__ tables,
    float2* __restrict__ ws)
{
    const int b = blockIdx.x;
    const int l = b / CHUNKS;          // level (block-uniform)
    const int c = b - l * CHUNKS;      // point chunk
    const int i = c * BLK + threadIdx.x;
    if (i >= NPTS) return;

    // single 12B load: 1 VMEM instr instead of 3
    const F3 p = *reinterpret_cast<const F3*>(x + 3 * (size_t)i);

    float f0, f1;
    switch (l) {
        case 0:  do_level<0 >(p.x, p.y, p.z, tables, f0, f1); break;
        case 1:  do_level<1 >(p.x, p.y, p.z, tables, f0, f1); break;
        case 2:  do_level<2 >(p.x, p.y, p.z, tables, f0, f1); break;
        case 3:  do_level<3 >(p.x, p.y, p.z, tables, f0, f1); break;
        case 4:  do_level<4 >(p.x, p.y, p.z, tables, f0, f1); break;
        case 5:  do_level<5 >(p.x, p.y, p.z, tables, f0, f1); break;
        case 6:  do_level<6 >(p.x, p.y, p.z, tables, f0, f1); break;
        case 7:  do_level<7 >(p.x, p.y, p.z, tables, f0, f1); break;
        case 8:  do_level<8 >(p.x, p.y, p.z, tables, f0, f1); break;
        case 9:  do_level<9 >(p.x, p.y, p.z, tables, f0, f1); break;
        case 10: do_level<10>(p.x, p.y, p.z, tables, f0, f1); break;
        case 11: do_level<11>(p.x, p.y, p.z, tables, f0, f1); break;
        case 12: do_level<12>(p.x, p.y, p.z, tables, f0, f1); break;
        case 13: do_level<13>(p.x, p.y, p.z, tables, f0, f1); break;
        case 14: do_level<14>(p.x, p.y, p.z, tables, f0, f1); break;
        default: do_level<15>(p.x, p.y, p.z, tables, f0, f1); break;
    }

    // nt store: written once, read once (pass2); don't evict the table from L2
    f32x2 o; o.x = f0; o.y = f1;
    __builtin_nontemporal_store(o,
        reinterpret_cast<f32x2*>(ws) + (size_t)l * NPTS + i);
}

// ---------------- Pass 2: wave-private transpose, barrier-free ----------------

__global__ __launch_bounds__(BLK) void hashgrid_pass2(
    const float* __restrict__ x,
    const float2* __restrict__ ws,
    float* __restrict__ out)
{
    __shared__ float smem[BLK * OUT_PP];   // 4 wave-private 8960B slices

    const int lane = threadIdx.x & 63;
    const int w    = threadIdx.x >> 6;
    const int tile = blockIdx.x * (BLK / 64) + w;   // 64-point tile
    if (tile >= TILES) return;                      // wave-uniform exit
    const int i = tile * 64 + lane;                 // always < NPTS (NPTS%64==0)

    float* s = smem + w * (64 * OUT_PP);

    const F3 p = *reinterpret_cast<const F3*>(x + 3 * (size_t)i);
    s[lane * OUT_PP + 0] = p.x;
    s[lane * OUT_PP + 1] = p.y;
    s[lane * OUT_PP + 2] = p.z;
    #pragma unroll
    for (int l = 0; l < NLEV; ++l) {
        const float2 v = ws[(size_t)l * NPTS + i];   // coalesced 8B
        s[lane * OUT_PP + 3 + 2 * l]     = v.x;
        s[lane * OUT_PP + 3 + 2 * l + 1] = v.y;
    }

    // wave-private LDS slice: only need this wave's DS ops complete, no barrier
    asm volatile("s_waitcnt lgkmcnt(0)" ::: "memory");

    const f32x4* __restrict__ s4 = reinterpret_cast<const f32x4*>(s);
    f32x4* __restrict__ o4 =
        reinterpret_cast<f32x4*>(out + (size_t)tile * (64 * OUT_PP));
    #pragma unroll
    for (int j = lane; j < (64 * OUT_PP) / 4; j += 64)   // 560 float4 / tile
        __builtin_nontemporal_store(s4[j], &o4[j]);
}

// ---------------- Fallback (point-major single kernel) ----------------

__global__ __launch_bounds__(BLK) void hashgrid_fused(
    const float* __restrict__ x,
    const float* __restrict__ tables,
    float* __restrict__ out)
{
    __shared__ float smem[BLK * OUT_PP];

    const int t = threadIdx.x;
    const int i = blockIdx.x * BLK + t;
    const bool active = (i < NPTS);

    float px = 0.f, py = 0.f, pz = 0.f;
    if (active) {
        const F3 p = *reinterpret_cast<const F3*>(x + 3 * (size_t)i);
        px = p.x; py = p.y; pz = p.z;
    }
    smem[t * OUT_PP + 0] = px;
    smem[t * OUT_PP + 1] = py;
    smem[t * OUT_PP + 2] = pz;

    float f0, f1;
    #pragma unroll
    for (int l = 0; l < NLEV; ++l) {
        switch (l) {
            case 0:  do_level<0 >(px, py, pz, tables, f0, f1); break;
            case 1:  do_level<1 >(px, py, pz, tables, f0, f1); break;
            case 2:  do_level<2 >(px, py, pz, tables, f0, f1); break;
            case 3:  do_level<3 >(px, py, pz, tables, f0, f1); break;
            case 4:  do_level<4 >(px, py, pz, tables, f0, f1); break;
            case 5:  do_level<5 >(px, py, pz, tables, f0, f1); break;
            case 6:  do_level<6 >(px, py, pz, tables, f0, f1); break;
            case 7:  do_level<7 >(px, py, pz, tables, f0, f1); break;
            case 8:  do_level<8 >(px, py, pz, tables, f0, f1); break;
            case 9:  do_level<9 >(px, py, pz, tables, f0, f1); break;
            case 10: do_level<10>(px, py, pz, tables, f0, f1); break;
            case 11: do_level<11>(px, py, pz, tables, f0, f1); break;
            case 12: do_level<12>(px, py, pz, tables, f0, f1); break;
            case 13: do_level<13>(px, py, pz, tables, f0, f1); break;
            case 14: do_level<14>(px, py, pz, tables, f0, f1); break;
            default: do_level<15>(px, py, pz, tables, f0, f1); break;
        }
        smem[t * OUT_PP + 3 + 2 * l]     = f0;
        smem[t * OUT_PP + 3 + 2 * l + 1] = f1;
    }

    __syncthreads();

    const size_t gbase = (size_t)blockIdx.x * (BLK * OUT_PP);
    const long long remain = (long long)NPTS * OUT_PP - (long long)gbase;
    const int n4 = (int)((remain < (long long)(BLK * OUT_PP) ? remain : (long long)(BLK * OUT_PP)) / 4);
    const float4* __restrict__ s4 = reinterpret_cast<const float4*>(smem);
    float4* __restrict__ o4 = reinterpret_cast<float4*>(out + gbase);
    for (int j = t; j < n4; j += BLK) o4[j] = s4[j];
}

extern "C" void kernel_launch(void* const* d_in, const int* in_sizes, int n_in,
                              void* d_out, int out_size, void* d_ws, size_t ws_size,
                              hipStream_t stream)
{
    const float* x      = (const float*)d_in[0];   // (1e6, 3) f32
    const float* tables = (const float*)d_in[1];   // (16, 2^19, 2) f32
    float* out          = (float*)d_out;           // (1e6, 35) f32

    const size_t ws_needed = (size_t)NLEV * NPTS * sizeof(float2);   // 128 MB

    if (ws_size >= ws_needed) {
        float2* ws = (float2*)d_ws;
        hashgrid_pass1<<<NLEV * CHUNKS, BLK, 0, stream>>>(x, tables, ws);
        hashgrid_pass2<<<P2BLOCKS, BLK, 0, stream>>>(x, ws, out);
    } else {
        hashgrid_fused<<<CHUNKS, BLK, 0, stream>>>(x, tables, out);
    }
}

// Round 4
// 552.136 us; speedup vs baseline: 1.1915x; 1.0067x over previous
//
#include <hip/hip_runtime.h>
#include <cstdint>
#include <cstddef>

// MultiResHashGrid encode: 1e6 points, 16 levels, 2 feats/level, 2^19 hashmap.
// Output per point: [x,y,z, f(l0,0),f(l0,1), ..., f(l15,0),f(l15,1)] = 35 f32.
//
// R5: pass1 is gather-request bound with an HBM-miss latency tail.
//   Evidence: R3 (+33% w/ 16B gathers) kills the line/byte models; R4 (-2% w/
//   17% fewer VMEM instrs) kills the instruction-slot model. Floor estimates:
//   TA 1 lane-req/cy -> 208us; L2->L1 line BW -> ~240us. Observed 349us.
//   FETCH=424MB vs ~76MB ideal => 4MB tables thrash in the 4MB XCD L2,
//   re-fetched ~6.6x/level from HBM (~900cy misses) -> the 1.5x gap.
//   Change: nt on the x point loads (no L1/L2 allocate; x lives in L3) so the
//   active table owns the XCD L2 exclusively. ws stores stay nt (R4, proven).
//   Predict: FETCH < 200MB, pass1 ~260-300us. If FETCH drops but time doesn't,
//   the TA floor is binding -> next: LDS tables / sorted points.
//   pass2: reverted to exact R2 form (183us measured; R4's barrier-free + nt
//   variant was +23us).

#define NPTS     1000000
#define NLEV     16
#define TBL_ENT  524288      // 2^19 entries per level
#define BLK      256
#define OUT_PP   35          // floats per point
#define CHUNKS   ((NPTS + BLK - 1) / BLK)   // 3907

typedef float f32x2 __attribute__((ext_vector_type(2)));

// r:  16  22  30  42  58  80  111  153  212  294  406  561  776  1072 1482 2048
// hs: min(r^3, 2^19)
constexpr float    cRes[NLEV] = {16.f, 22.f, 30.f, 42.f, 58.f, 80.f, 111.f, 153.f,
                                 212.f, 294.f, 406.f, 561.f, 776.f, 1072.f, 1482.f, 2048.f};
constexpr uint32_t cHS[NLEV]  = {4096u, 10648u, 27000u, 74088u, 195112u, 512000u,
                                 524288u, 524288u, 524288u, 524288u, 524288u,
                                 524288u, 524288u, 524288u, 524288u, 524288u};

// ---------------- per-level gather (R2 form), compile-time level params ----------------

template<int L>
__device__ __forceinline__ void do_level(float px, float py, float pz,
                                         const float* __restrict__ tables,
                                         float& f0, float& f1)
{
    constexpr float    r  = cRes[L];
    constexpr uint32_t hs = cHS[L];
    const float2* __restrict__ tbl =
        reinterpret_cast<const float2*>(tables) + (size_t)L * TBL_ENT;

    const float xs = px * r, ys = py * r, zs = pz * r;
    const int xi = (int)xs, yi = (int)ys, zi = (int)zs;
    const float xf = xs - (float)xi, yf = ys - (float)yi, zf = zs - (float)zi;

    const uint32_t hx0 = (uint32_t)xi;
    const uint32_t hx1 = hx0 + 1u;
    const uint32_t hy0 = (uint32_t)yi * 2654435761u;
    const uint32_t hy1 = hy0 + 2654435761u;
    const uint32_t hz0 = (uint32_t)zi * 805459861u;
    const uint32_t hz1 = hz0 + 805459861u;

    const float wx0 = 1.f - xf, wx1 = xf;
    const float wy0 = 1.f - yf, wy1 = yf;
    const float wz0 = 1.f - zf, wz1 = zf;

    uint32_t hid[8];
    float    w[8];
    #pragma unroll
    for (int c = 0; c < 8; ++c) {
        const uint32_t hxc = (c & 1) ? hx1 : hx0;
        const uint32_t hyc = (c & 2) ? hy1 : hy0;
        const uint32_t hzc = (c & 4) ? hz1 : hz0;
        hid[c] = (hxc ^ hyc ^ hzc) % hs;   // hs compile-time: AND or magic-mul
        const float wxc = (c & 1) ? wx1 : wx0;
        const float wyc = (c & 2) ? wy1 : wy0;
        const float wzc = (c & 4) ? wz1 : wz0;
        w[c] = wxc * wyc * wzc;
    }

    float2 v[8];
    #pragma unroll
    for (int c = 0; c < 8; ++c) v[c] = tbl[hid[c]];

    f0 = 0.f; f1 = 0.f;
    #pragma unroll
    for (int c = 0; c < 8; ++c) {
        f0 = fmaf(w[c], v[c].x, f0);
        f1 = fmaf(w[c], v[c].y, f1);
    }
}

// ---------------- Pass 1: level-major gather ----------------

__global__ __launch_bounds__(BLK) void hashgrid_pass1(
    const float* __restrict__ x,
    const float* __restrict__ tables,
    float2* __restrict__ ws)
{
    const int b = blockIdx.x;
    const int l = b / CHUNKS;          // level (block-uniform)
    const int c = b - l * CHUNKS;      // point chunk
    const int i = c * BLK + threadIdx.x;
    if (i >= NPTS) return;

    // nt loads: no L1/L2 allocate -> x served from L3 (12MB resident),
    // the active 4MB table keeps the XCD L2 to itself.
    const float px = __builtin_nontemporal_load(&x[3 * i + 0]);
    const float py = __builtin_nontemporal_load(&x[3 * i + 1]);
    const float pz = __builtin_nontemporal_load(&x[3 * i + 2]);

    float f0, f1;
    switch (l) {
        case 0:  do_level<0 >(px, py, pz, tables, f0, f1); break;
        case 1:  do_level<1 >(px, py, pz, tables, f0, f1); break;
        case 2:  do_level<2 >(px, py, pz, tables, f0, f1); break;
        case 3:  do_level<3 >(px, py, pz, tables, f0, f1); break;
        case 4:  do_level<4 >(px, py, pz, tables, f0, f1); break;
        case 5:  do_level<5 >(px, py, pz, tables, f0, f1); break;
        case 6:  do_level<6 >(px, py, pz, tables, f0, f1); break;
        case 7:  do_level<7 >(px, py, pz, tables, f0, f1); break;
        case 8:  do_level<8 >(px, py, pz, tables, f0, f1); break;
        case 9:  do_level<9 >(px, py, pz, tables, f0, f1); break;
        case 10: do_level<10>(px, py, pz, tables, f0, f1); break;
        case 11: do_level<11>(px, py, pz, tables, f0, f1); break;
        case 12: do_level<12>(px, py, pz, tables, f0, f1); break;
        case 13: do_level<13>(px, py, pz, tables, f0, f1); break;
        case 14: do_level<14>(px, py, pz, tables, f0, f1); break;
        default: do_level<15>(px, py, pz, tables, f0, f1); break;
    }

    // nt store: written once, read once (pass2); don't evict the table from L2
    f32x2 o; o.x = f0; o.y = f1;
    __builtin_nontemporal_store(o,
        reinterpret_cast<f32x2*>(ws) + (size_t)l * NPTS + i);
}

// ---------------- Pass 2: transpose ws (level-major) -> out (point-major) ----------------
// Exact R2 form (measured 183us): block-wide LDS + __syncthreads + float4 stores.

__global__ __launch_bounds__(BLK) void hashgrid_pass2(
    const float* __restrict__ x,
    const float2* __restrict__ ws,
    float* __restrict__ out)
{
    __shared__ float smem[BLK * OUT_PP];   // 35840 B

    const int t = threadIdx.x;
    const int base = blockIdx.x * BLK;
    const int i = base + t;
    const bool active = (i < NPTS);

    if (active) {
        smem[t * OUT_PP + 0] = x[3 * i + 0];
        smem[t * OUT_PP + 1] = x[3 * i + 1];
        smem[t * OUT_PP + 2] = x[3 * i + 2];
        #pragma unroll
        for (int l = 0; l < NLEV; ++l) {
            const float2 v = ws[(size_t)l * NPTS + i];   // coalesced 8B
            smem[t * OUT_PP + 3 + 2 * l]     = v.x;
            smem[t * OUT_PP + 3 + 2 * l + 1] = v.y;
        }
    }
    __syncthreads();

    const size_t gbase = (size_t)blockIdx.x * (BLK * OUT_PP);
    const long long remain = (long long)NPTS * OUT_PP - (long long)gbase;
    const int n4 = (int)((remain < (long long)(BLK * OUT_PP) ? remain : (long long)(BLK * OUT_PP)) / 4);
    const float4* __restrict__ s4 = reinterpret_cast<const float4*>(smem);
    float4* __restrict__ o4 = reinterpret_cast<float4*>(out + gbase);
    for (int j = t; j < n4; j += BLK) o4[j] = s4[j];
}

// ---------------- Fallback (point-major single kernel) ----------------

__global__ __launch_bounds__(BLK) void hashgrid_fused(
    const float* __restrict__ x,
    const float* __restrict__ tables,
    float* __restrict__ out)
{
    __shared__ float smem[BLK * OUT_PP];

    const int t = threadIdx.x;
    const int i = blockIdx.x * BLK + t;
    const bool active = (i < NPTS);

    float px = 0.f, py = 0.f, pz = 0.f;
    if (active) {
        px = x[3 * i + 0];
        py = x[3 * i + 1];
        pz = x[3 * i + 2];
    }
    smem[t * OUT_PP + 0] = px;
    smem[t * OUT_PP + 1] = py;
    smem[t * OUT_PP + 2] = pz;

    float f0, f1;
    #pragma unroll
    for (int l = 0; l < NLEV; ++l) {
        switch (l) {
            case 0:  do_level<0 >(px, py, pz, tables, f0, f1); break;
            case 1:  do_level<1 >(px, py, pz, tables, f0, f1); break;
            case 2:  do_level<2 >(px, py, pz, tables, f0, f1); break;
            case 3:  do_level<3 >(px, py, pz, tables, f0, f1); break;
            case 4:  do_level<4 >(px, py, pz, tables, f0, f1); break;
            case 5:  do_level<5 >(px, py, pz, tables, f0, f1); break;
            case 6:  do_level<6 >(px, py, pz, tables, f0, f1); break;
            case 7:  do_level<7 >(px, py, pz, tables, f0, f1); break;
            case 8:  do_level<8 >(px, py, pz, tables, f0, f1); break;
            case 9:  do_level<9 >(px, py, pz, tables, f0, f1); break;
            case 10: do_level<10>(px, py, pz, tables, f0, f1); break;
            case 11: do_level<11>(px, py, pz, tables, f0, f1); break;
            case 12: do_level<12>(px, py, pz, tables, f0, f1); break;
            case 13: do_level<13>(px, py, pz, tables, f0, f1); break;
            case 14: do_level<14>(px, py, pz, tables, f0, f1); break;
            default: do_level<15>(px, py, pz, tables, f0, f1); break;
        }
        smem[t * OUT_PP + 3 + 2 * l]     = f0;
        smem[t * OUT_PP + 3 + 2 * l + 1] = f1;
    }

    __syncthreads();

    const size_t gbase = (size_t)blockIdx.x * (BLK * OUT_PP);
    const long long remain = (long long)NPTS * OUT_PP - (long long)gbase;
    const int n4 = (int)((remain < (long long)(BLK * OUT_PP) ? remain : (long long)(BLK * OUT_PP)) / 4);
    const float4* __restrict__ s4 = reinterpret_cast<const float4*>(smem);
    float4* __restrict__ o4 = reinterpret_cast<float4*>(out + gbase);
    for (int j = t; j < n4; j += BLK) o4[j] = s4[j];
}

extern "C" void kernel_launch(void* const* d_in, const int* in_sizes, int n_in,
                              void* d_out, int out_size, void* d_ws, size_t ws_size,
                              hipStream_t stream)
{
    const float* x      = (const float*)d_in[0];   // (1e6, 3) f32
    const float* tables = (const float*)d_in[1];   // (16, 2^19, 2) f32
    float* out          = (float*)d_out;           // (1e6, 35) f32

    const size_t ws_needed = (size_t)NLEV * NPTS * sizeof(float2);   // 128 MB

    if (ws_size >= ws_needed) {
        float2* ws = (float2*)d_ws;
        hashgrid_pass1<<<NLEV * CHUNKS, BLK, 0, stream>>>(x, tables, ws);
        hashgrid_pass2<<<CHUNKS, BLK, 0, stream>>>(x, ws, out);
    } else {
        hashgrid_fused<<<CHUNKS, BLK, 0, stream>>>(x, tables, out);
    }
}